// Round 1
// baseline (4848.024 us; speedup 1.0000x reference)
//
#include <hip/hip_runtime.h>

#define BB 16
#define NN 2048
#define NITERS 100

// k = log2(e)/eps, eps = 0.05
#define K2E      28.853900817779268f
#define TWO_K2E  57.707801635558536f
#define INV2K    0.017328679513998632f   // 1/(2k)
#define INV_K2E  0.034657359027997264f
#define INV4K    0.008664339756999316f   // 1/(4k)
#define LMU      (-11.0f)                // log2(1/2048)

#if __has_builtin(__builtin_amdgcn_exp2f)
#define EXP2F(x) __builtin_amdgcn_exp2f(x)
#else
#define EXP2F(x) exp2f(x)
#endif

typedef float v2f __attribute__((ext_vector_type(2)));

// device-coherent (LLC-homed, sc1) accessors for the dual arrays
#define DSTORE(p, v) __hip_atomic_store((p), (v), __ATOMIC_RELAXED, __HIP_MEMORY_SCOPE_AGENT)
#define DLOAD(p)     __hip_atomic_load((p), __ATOMIC_RELAXED, __HIP_MEMORY_SCOPE_AGENT)

// Sum-pass: 8 rows/wave (coords from LDS, raw = u*INV2K), own j-half of LDS
// SoA tables t0..t2; dual read DIRECTLY from LLC (sc1), 16 preloaded values
// consumed across the pass. Packed-f32 d-computation. Returns combined
// row-sum on lanes 0..7.  (UNCHANGED from verified version.)
__device__ __forceinline__ float sumpassG(
    const float* __restrict__ u0, const float* __restrict__ u1,
    const float* __restrict__ u2,
    const float* __restrict__ t0, const float* __restrict__ t1,
    const float* __restrict__ t2, const float* __restrict__ gd,
    int rloc, int jh, int lane, int w, float* pcomb)
{
    const int jb = (jh << 10) + lane;
    float dv[16];
    #pragma unroll
    for (int s = 0; s < 16; ++s)
        dv[s] = DLOAD(gd + jb + (s << 6));

    v2f xp0[4], xp1[4], xp2[4], acc2[4];
    #pragma unroll
    for (int p = 0; p < 4; ++p) {
        xp0[p] = (v2f){u0[rloc + 2*p] * INV2K, u0[rloc + 2*p + 1] * INV2K};
        xp1[p] = (v2f){u1[rloc + 2*p] * INV2K, u1[rloc + 2*p + 1] * INV2K};
        xp2[p] = (v2f){u2[rloc + 2*p] * INV2K, u2[rloc + 2*p + 1] * INV2K};
        acc2[p] = (v2f){0.f, 0.f};
    }
    #pragma unroll 2
    for (int s = 0; s < 16; ++s) {
        const int p = jb + (s << 6);
        const float a0 = t0[p], a1 = t1[p], a2 = t2[p], ad = dv[s];
        const v2f a0v = (v2f){a0, a0}, a1v = (v2f){a1, a1};
        const v2f a2v = (v2f){a2, a2}, adv = (v2f){ad, ad};
        #pragma unroll
        for (int q = 0; q < 4; ++q) {
            v2f d = __builtin_elementwise_fma(xp0[q], a0v,
                    __builtin_elementwise_fma(xp1[q], a1v,
                    __builtin_elementwise_fma(xp2[q], a2v, adv)));
            acc2[q] += (v2f){EXP2F(d.x), EXP2F(d.y)};
        }
    }
    float acc[8];
    #pragma unroll
    for (int p = 0; p < 4; ++p) { acc[2*p] = acc2[p].x; acc[2*p+1] = acc2[p].y; }
    // multi-value butterfly (verified R3/R5/R8); lanes<8 end with row rr
    const bool b0 = lane & 1, b1 = lane & 2, b2 = lane & 4;
    float v4[4], v2_[2], v1;
    #pragma unroll
    for (int i = 0; i < 4; ++i) {
        float recv = __shfl_xor(b0 ? acc[i] : acc[i+4], 1, 64);
        v4[i] = (b0 ? acc[i+4] : acc[i]) + recv;
    }
    #pragma unroll
    for (int i = 0; i < 2; ++i) {
        float recv = __shfl_xor(b1 ? v4[i] : v4[i+2], 2, 64);
        v2_[i] = (b1 ? v4[i+2] : v4[i]) + recv;
    }
    {
        float recv = __shfl_xor(b2 ? v2_[0] : v2_[1], 4, 64);
        v1 = (b2 ? v2_[1] : v2_[0]) + recv;
    }
    v1 += __shfl_xor(v1, 8, 64);
    v1 += __shfl_xor(v1, 16, 64);
    v1 += __shfl_xor(v1, 32, 64);
    const int rr = ((lane & 1) << 2) | (lane & 2) | ((lane >> 2) & 1);
    if (lane < 8) pcomb[w * 8 + rr] = v1;
    __syncthreads();
    float S = 0.f;
    if (lane < 8) S = v1 + pcomb[(w ^ 1) * 8 + rr];
    return S;
}

// Epilogue partial: sum_j P_ij*C_ij, 8 rows x own j-half. (UNCHANGED.)
__device__ __forceinline__ float epilG(
    const float* __restrict__ u0, const float* __restrict__ u1,
    const float* __restrict__ u2,
    const float* __restrict__ t0, const float* __restrict__ t1,
    const float* __restrict__ t2, const float* __restrict__ gB,
    float Aval, int rloc, int jh, int lane)
{
    const int jb = (jh << 10) + lane;
    float dv[16];
    #pragma unroll
    for (int s = 0; s < 16; ++s)
        dv[s] = DLOAD(gB + jb + (s << 6));

    float xr0[8], xr1[8], xr2[8], Ak[8], x2k[8];
    #pragma unroll
    for (int k = 0; k < 8; ++k) {
        xr0[k] = u0[rloc + k] * INV2K;
        xr1[k] = u1[rloc + k] * INV2K;
        xr2[k] = u2[rloc + k] * INV2K;
        const int src = ((k & 1) << 2) | (k & 2) | ((k >> 2) & 1);
        Ak[k]  = __shfl(Aval, src, 64);
        x2k[k] = K2E * (xr0[k]*xr0[k] + xr1[k]*xr1[k] + xr2[k]*xr2[k]);
    }
    float acc = 0.f;
    for (int s = 0; s < 16; ++s) {
        const int p = jb + (s << 6);
        const float a0 = t0[p], a1 = t1[p], a2 = t2[p], tb = dv[s];
        const float q2 = (a0*a0 + a1*a1 + a2*a2) * INV4K;   // k|y|^2
        #pragma unroll
        for (int k = 0; k < 8; ++k) {
            float d = fmaf(xr0[k], a0, fmaf(xr1[k], a1, fmaf(xr2[k], a2, tb)));
            float P = EXP2F(d + Ak[k]);                       // exp(logP)
            float C = fmaxf((x2k[k] + q2 - (d - tb)) * INV_K2E, 0.f);
            acc = fmaf(P, C, acc);
        }
    }
    return acc;
}

// NEW GEOMETRY (R13): 512 blocks x 1024 threads, 2 blocks/CU (48 KB LDS each,
// VGPR capped at 64 via launch_bounds(1024,8)) -> 8 waves/SIMD, double the
// latency hiding. Each block owns ONE batch (b = blk & 15, so co-resident
// blocks belong to different batch groups and overlap each other's waits)
// and 64 rows (q = blk >> 4). Per iteration: f-phase, post+wait(all 32 peers),
// g-phase, post+wait. Zero-slack waits; every wave polls its own flag copy
// (no trailing barrier) so each wave launches its LLC dual preload the
// moment its data is ready.
__global__ __launch_bounds__(1024, 8) void emd_sinkhorn(
    const float* __restrict__ x, const float* __restrict__ y,
    float* __restrict__ Af, float* __restrict__ Bf,
    int* __restrict__ flags, float* __restrict__ out)
{
    extern __shared__ float S[];     // 6*NN floats = 48 KB
    __shared__ float pcomb[16 * 8];
    __shared__ float wsum[16];

    const int tid  = threadIdx.x;
    const int lane = tid & 63;
    const int w    = tid >> 6;        // 0..15
    const int pr   = w >> 1;          // row-group 0..7
    const int jh   = w & 1;           // j-half
    const int blk  = blockIdx.x;
    const int b    = blk & 15;        // batch (co-residents differ)
    const int q    = blk >> 4;        // 0..31: row-slice within batch
    const int base = b * NN;
    const int rloc = q * 64 + pr * 8; // within-batch row base
    int* fb = flags + b * 128;        // 32 slots x 16 B per batch

    // LDS carve: 6 table slots of NN floats (SoA — conflict-free)
    float *sy0 = S,        *sy1 = S +   NN, *sy2 = S + 2*NN;
    float *sx0 = S + 3*NN, *sx1 = S + 4*NN, *sx2 = S + 5*NN;

    // ---- prologue: stage 2k-scaled tables for own batch ----
    #pragma unroll
    for (int v = 0; v < 2; ++v) {
        const int p = tid + (v << 10);
        const float* px = x + 3 * (size_t)(base + p);
        sx0[p] = TWO_K2E * px[0]; sx1[p] = TWO_K2E * px[1]; sx2[p] = TWO_K2E * px[2];
        const float* py = y + 3 * (size_t)(base + p);
        sy0[p] = TWO_K2E * py[0]; sy1[p] = TWO_K2E * py[1]; sy2[p] = TWO_K2E * py[2];
    }
    // ---- prologue: B0-init for own 64 columns (sc1) ----
    if (tid < 64) {
        const int col = q * 64 + tid;
        const float* py = y + 3 * (size_t)(base + col);
        const float a = py[0], bb = py[1], c = py[2];
        DSTORE(&Bf[base + col], -K2E * (a*a + bb*bb + c*c));
    }

    // post own phase counter + wait all 32 peer slots; every wave polls.
    // Entry __syncthreads drains all waves' stores (compiler emits
    // vmcnt(0) before s_barrier) before tid0's release post — same
    // visibility pattern as the verified 2-batch kernel.
    #define PW(pval, tgt) do { __syncthreads();                                 \
        if (tid == 0)                                                           \
            __hip_atomic_store(fb + q * 4, (pval), __ATOMIC_RELEASE,            \
                               __HIP_MEMORY_SCOPE_AGENT);                       \
        for (;;) {                                                              \
            int vv = (lane < 32)                                                \
                ? __hip_atomic_load(fb + lane * 4, __ATOMIC_RELAXED,            \
                                    __HIP_MEMORY_SCOPE_AGENT)                   \
                : 0x7fffffff;                                                   \
            if (__ballot(vv >= (tgt)) == ~0ULL) break;                          \
            __builtin_amdgcn_s_sleep(1);                                        \
        }                                                                       \
    } while (0)

    PW(1, 1);                         // init-B ready across the batch group

    const int rr = ((lane & 1) << 2) | (lane & 2) | ((lane >> 2) & 1);
    float Aval = 0.f;

    for (int it = 0; it < NITERS; ++it) {
        // ---- f-phase: dual = Bf (g of it-1 / init) ----
        {
            float Sc = sumpassG(sx0, sx1, sx2, sy0, sy1, sy2, Bf + base,
                                rloc, jh, lane, w, pcomb);
            Aval = LMU - __log2f(Sc);
            if (lane < 8 && jh == 0) DSTORE(&Af[base + rloc + rr], Aval);
        }
        PW(2 * it + 2, 2 * it + 2);   // post f; wait all peers' f
        // ---- g-phase: dual = Af ----
        {
            float Sc = sumpassG(sy0, sy1, sy2, sx0, sx1, sx2, Af + base,
                                rloc, jh, lane, w, pcomb);
            if (lane < 8 && jh == 0)
                DSTORE(&Bf[base + rloc + rr], LMU - __log2f(Sc));
        }
        PW(2 * it + 3, 2 * it + 3);   // post g; wait all peers' g
    }
    // last PW(2*99+3=201) already guarantees final Bf complete for epilogue

    // ---- epilogue: own 64 rows, own j-half ----
    {
        float s = epilG(sx0, sx1, sx2, sy0, sy1, sy2, Bf + base,
                        Aval, rloc, jh, lane);
        #pragma unroll
        for (int m = 32; m > 0; m >>= 1) s += __shfl_xor(s, m, 64);
        if (lane == 0) wsum[w] = s;
        __syncthreads();
        if (tid == 0) {
            float t = 0.f;
            #pragma unroll
            for (int i = 0; i < 16; ++i) t += wsum[i];
            atomicAdd(out, t * (1.0f / (float)BB));
        }
    }
    #undef PW
}

extern "C" void kernel_launch(void* const* d_in, const int* in_sizes, int n_in,
                              void* d_out, int out_size, void* d_ws, size_t ws_size,
                              hipStream_t stream) {
    const float* x = (const float*)d_in[0];
    const float* y = (const float*)d_in[1];
    float* out = (float*)d_out;
    char* ws = (char*)d_ws;

    int*   flags = (int*)ws;                                 // 16 x 32 x 16 B = 8 KB
    float* Af    = (float*)(ws + 8192);                      // 128 KB
    float* Bf    = (float*)(ws + 8192 + (size_t)BB*NN*sizeof(float));

    hipMemsetAsync(flags, 0, 8192, stream);
    hipMemsetAsync(out, 0, sizeof(float), stream);

    const size_t shmem = (size_t)6 * NN * sizeof(float);     // 48 KB
    hipFuncSetAttribute((const void*)emd_sinkhorn,
                        hipFuncAttributeMaxDynamicSharedMemorySize, (int)shmem);

    void* args[] = {(void*)&x, (void*)&y, (void*)&Af, (void*)&Bf,
                    (void*)&flags, (void*)&out};
    hipError_t e = hipLaunchCooperativeKernel((const void*)emd_sinkhorn,
                                              dim3(512), dim3(1024),
                                              args, shmem, stream);
    if (e != hipSuccess) {
        // 2 blocks/CU occupancy is compile-time guaranteed (launch_bounds
        // caps VGPR at 64, LDS 48.6 KB < 80 KB), so 512 blocks are
        // co-resident even under a plain launch.
        hipLaunchKernelGGL(emd_sinkhorn, dim3(512), dim3(1024), shmem, stream,
                           x, y, Af, Bf, flags, out);
    }
}

// Round 2
// 3205.356 us; speedup vs baseline: 1.5125x; 1.5125x over previous
//
#include <hip/hip_runtime.h>

#define BB 16
#define NN 2048
#define NITERS 100

// k = log2(e)/eps, eps = 0.05
#define K2E      28.853900817779268f
#define TWO_K2E  57.707801635558536f
#define INV2K    0.017328679513998632f   // 1/(2k)
#define INV_K2E  0.034657359027997264f
#define INV4K    0.008664339756999316f   // 1/(4k)
#define LMU      (-11.0f)                // log2(1/2048)

#if __has_builtin(__builtin_amdgcn_exp2f)
#define EXP2F(x) __builtin_amdgcn_exp2f(x)
#else
#define EXP2F(x) exp2f(x)
#endif

typedef float v2f __attribute__((ext_vector_type(2)));

// device-coherent (LLC-homed, sc1) accessors for the dual arrays
#define DSTORE(p, v) __hip_atomic_store((p), (v), __ATOMIC_RELAXED, __HIP_MEMORY_SCOPE_AGENT)
#define DLOAD(p)     __hip_atomic_load((p), __ATOMIC_RELAXED, __HIP_MEMORY_SCOPE_AGENT)

// Sum-pass: 8 rows/wave (coords from LDS, raw = u*INV2K), own j-half of LDS
// SoA tables t0..t2; dual read DIRECTLY from LLC (sc1), 16 preloaded values
// consumed across the pass. Packed-f32 d-computation. Returns combined
// row-sum on lanes 0..7.  (UNCHANGED from verified version.)
__device__ __forceinline__ float sumpassG(
    const float* __restrict__ u0, const float* __restrict__ u1,
    const float* __restrict__ u2,
    const float* __restrict__ t0, const float* __restrict__ t1,
    const float* __restrict__ t2, const float* __restrict__ gd,
    int rloc, int jh, int lane, int w, float* pcomb)
{
    const int jb = (jh << 10) + lane;
    float dv[16];
    #pragma unroll
    for (int s = 0; s < 16; ++s)
        dv[s] = DLOAD(gd + jb + (s << 6));

    v2f xp0[4], xp1[4], xp2[4], acc2[4];
    #pragma unroll
    for (int p = 0; p < 4; ++p) {
        xp0[p] = (v2f){u0[rloc + 2*p] * INV2K, u0[rloc + 2*p + 1] * INV2K};
        xp1[p] = (v2f){u1[rloc + 2*p] * INV2K, u1[rloc + 2*p + 1] * INV2K};
        xp2[p] = (v2f){u2[rloc + 2*p] * INV2K, u2[rloc + 2*p + 1] * INV2K};
        acc2[p] = (v2f){0.f, 0.f};
    }
    #pragma unroll 2
    for (int s = 0; s < 16; ++s) {
        const int p = jb + (s << 6);
        const float a0 = t0[p], a1 = t1[p], a2 = t2[p], ad = dv[s];
        const v2f a0v = (v2f){a0, a0}, a1v = (v2f){a1, a1};
        const v2f a2v = (v2f){a2, a2}, adv = (v2f){ad, ad};
        #pragma unroll
        for (int q = 0; q < 4; ++q) {
            v2f d = __builtin_elementwise_fma(xp0[q], a0v,
                    __builtin_elementwise_fma(xp1[q], a1v,
                    __builtin_elementwise_fma(xp2[q], a2v, adv)));
            acc2[q] += (v2f){EXP2F(d.x), EXP2F(d.y)};
        }
    }
    float acc[8];
    #pragma unroll
    for (int p = 0; p < 4; ++p) { acc[2*p] = acc2[p].x; acc[2*p+1] = acc2[p].y; }
    // multi-value butterfly (verified R3/R5/R8); lanes<8 end with row rr
    const bool b0 = lane & 1, b1 = lane & 2, b2 = lane & 4;
    float v4[4], v2_[2], v1;
    #pragma unroll
    for (int i = 0; i < 4; ++i) {
        float recv = __shfl_xor(b0 ? acc[i] : acc[i+4], 1, 64);
        v4[i] = (b0 ? acc[i+4] : acc[i]) + recv;
    }
    #pragma unroll
    for (int i = 0; i < 2; ++i) {
        float recv = __shfl_xor(b1 ? v4[i] : v4[i+2], 2, 64);
        v2_[i] = (b1 ? v4[i+2] : v4[i]) + recv;
    }
    {
        float recv = __shfl_xor(b2 ? v2_[0] : v2_[1], 4, 64);
        v1 = (b2 ? v2_[1] : v2_[0]) + recv;
    }
    v1 += __shfl_xor(v1, 8, 64);
    v1 += __shfl_xor(v1, 16, 64);
    v1 += __shfl_xor(v1, 32, 64);
    const int rr = ((lane & 1) << 2) | (lane & 2) | ((lane >> 2) & 1);
    if (lane < 8) pcomb[w * 8 + rr] = v1;
    __syncthreads();
    float S = 0.f;
    if (lane < 8) S = v1 + pcomb[(w ^ 1) * 8 + rr];
    return S;
}

// Epilogue partial: sum_j P_ij*C_ij, 8 rows x own j-half. (UNCHANGED.)
__device__ __forceinline__ float epilG(
    const float* __restrict__ u0, const float* __restrict__ u1,
    const float* __restrict__ u2,
    const float* __restrict__ t0, const float* __restrict__ t1,
    const float* __restrict__ t2, const float* __restrict__ gB,
    float Aval, int rloc, int jh, int lane)
{
    const int jb = (jh << 10) + lane;
    float dv[16];
    #pragma unroll
    for (int s = 0; s < 16; ++s)
        dv[s] = DLOAD(gB + jb + (s << 6));

    float xr0[8], xr1[8], xr2[8], Ak[8], x2k[8];
    #pragma unroll
    for (int k = 0; k < 8; ++k) {
        xr0[k] = u0[rloc + k] * INV2K;
        xr1[k] = u1[rloc + k] * INV2K;
        xr2[k] = u2[rloc + k] * INV2K;
        const int src = ((k & 1) << 2) | (k & 2) | ((k >> 2) & 1);
        Ak[k]  = __shfl(Aval, src, 64);
        x2k[k] = K2E * (xr0[k]*xr0[k] + xr1[k]*xr1[k] + xr2[k]*xr2[k]);
    }
    float acc = 0.f;
    for (int s = 0; s < 16; ++s) {
        const int p = jb + (s << 6);
        const float a0 = t0[p], a1 = t1[p], a2 = t2[p], tb = dv[s];
        const float q2 = (a0*a0 + a1*a1 + a2*a2) * INV4K;   // k|y|^2
        #pragma unroll
        for (int k = 0; k < 8; ++k) {
            float d = fmaf(xr0[k], a0, fmaf(xr1[k], a1, fmaf(xr2[k], a2, tb)));
            float P = EXP2F(d + Ak[k]);                       // exp(logP)
            float C = fmaxf((x2k[k] + q2 - (d - tb)) * INV_K2E, 0.f);
            acc = fmaf(P, C, acc);
        }
    }
    return acc;
}

// R14 geometry: 512 blocks x 1024 threads, one batch per block.
//  - NO min-waves clamp: launch_bounds(1024) only, so the compiler keeps the
//    64-VGPR allocation the inner pass needs for its 16 in-flight LLC
//    preloads (R13's ",8" forced 32 VGPRs -> serialized loads -> 36% VALU).
//    64 VGPR is exactly the 8-waves/SIMD HW threshold, so 2 blocks/CU still
//    co-schedule (48.6 KB LDS x2 < 160 KB; 16 waves x2 = 32/CU).
//  - batch = blk >> 5 so co-resident blocks (blk, blk+256 under round-robin
//    XCD dispatch: CU c of XCD x holds blocks 8c+x+256k) are batches b and
//    b+8: DIFFERENT sync groups. One block computes while the other waits.
//    (R13's blk&15 made co-residents the SAME batch -> synchronized stalls.)
//  - wave-0-only flag polling + barriers (R12-verified pattern).
__global__ __launch_bounds__(1024) void emd_sinkhorn1(
    const float* __restrict__ x, const float* __restrict__ y,
    float* __restrict__ Af, float* __restrict__ Bf,
    int* __restrict__ flags, float* __restrict__ out)
{
    extern __shared__ float S[];     // 6*NN floats = 48 KB
    __shared__ float pcomb[16 * 8];
    __shared__ float wsum[16];

    const int tid  = threadIdx.x;
    const int lane = tid & 63;
    const int w    = tid >> 6;        // 0..15
    const int pr   = w >> 1;          // row-group 0..7
    const int jh   = w & 1;           // j-half
    const int blk  = blockIdx.x;
    const int b    = blk >> 5;        // batch 0..15 (co-residents differ by 8)
    const int q    = blk & 31;        // row-slice within batch
    const int base = b * NN;
    const int rloc = q * 64 + pr * 8; // within-batch row base
    int* fb = flags + b * 128;        // 32 slots x 16 B per batch

    // LDS carve: 6 table slots of NN floats (SoA — conflict-free)
    float *sy0 = S,        *sy1 = S +   NN, *sy2 = S + 2*NN;
    float *sx0 = S + 3*NN, *sx1 = S + 4*NN, *sx2 = S + 5*NN;

    // ---- prologue: stage 2k-scaled tables for own batch ----
    #pragma unroll
    for (int v = 0; v < 2; ++v) {
        const int p = tid + (v << 10);
        const float* px = x + 3 * (size_t)(base + p);
        sx0[p] = TWO_K2E * px[0]; sx1[p] = TWO_K2E * px[1]; sx2[p] = TWO_K2E * px[2];
        const float* py = y + 3 * (size_t)(base + p);
        sy0[p] = TWO_K2E * py[0]; sy1[p] = TWO_K2E * py[1]; sy2[p] = TWO_K2E * py[2];
    }
    // ---- prologue: B0-init for own 64 columns (sc1) ----
    if (tid < 64) {
        const int col = q * 64 + tid;
        const float* py = y + 3 * (size_t)(base + col);
        const float a = py[0], bb = py[1], c = py[2];
        DSTORE(&Bf[base + col], -K2E * (a*a + bb*bb + c*c));
    }

    // post own phase counter + wait all 32 peer slots (wave 0 polls).
    // Entry __syncthreads drains all waves' DSTOREs (compiler emits
    // vmcnt(0) before s_barrier) before tid0's release post.
    #define PW(pval, tgt) do { __syncthreads();                                 \
        if (tid == 0)                                                           \
            __hip_atomic_store(fb + q * 4, (pval), __ATOMIC_RELEASE,            \
                               __HIP_MEMORY_SCOPE_AGENT);                       \
        if (w == 0) {                                                           \
            for (;;) {                                                          \
                int vv = (lane < 32)                                            \
                    ? __hip_atomic_load(fb + lane * 4, __ATOMIC_RELAXED,        \
                                        __HIP_MEMORY_SCOPE_AGENT)               \
                    : 0x7fffffff;                                               \
                if (__ballot(vv >= (tgt)) == ~0ULL) break;                      \
                __builtin_amdgcn_s_sleep(1);                                    \
            }                                                                   \
        }                                                                       \
        __syncthreads(); } while (0)

    PW(1, 1);                         // init-B ready across the batch group

    const int rr = ((lane & 1) << 2) | (lane & 2) | ((lane >> 2) & 1);
    float Aval = 0.f;

    for (int it = 0; it < NITERS; ++it) {
        // ---- f-phase: dual = Bf (g of it-1 / init) ----
        {
            float Sc = sumpassG(sx0, sx1, sx2, sy0, sy1, sy2, Bf + base,
                                rloc, jh, lane, w, pcomb);
            Aval = LMU - __log2f(Sc);
            if (lane < 8 && jh == 0) DSTORE(&Af[base + rloc + rr], Aval);
        }
        PW(2 * it + 2, 2 * it + 2);   // post f; wait all peers' f
        // ---- g-phase: dual = Af ----
        {
            float Sc = sumpassG(sy0, sy1, sy2, sx0, sx1, sx2, Af + base,
                                rloc, jh, lane, w, pcomb);
            if (lane < 8 && jh == 0)
                DSTORE(&Bf[base + rloc + rr], LMU - __log2f(Sc));
        }
        PW(2 * it + 3, 2 * it + 3);   // post g; wait all peers' g
    }
    // last PW (target 201) guarantees final Bf complete for epilogue

    // ---- epilogue: own 64 rows, own j-half ----
    {
        float s = epilG(sx0, sx1, sx2, sy0, sy1, sy2, Bf + base,
                        Aval, rloc, jh, lane);
        #pragma unroll
        for (int m = 32; m > 0; m >>= 1) s += __shfl_xor(s, m, 64);
        if (lane == 0) wsum[w] = s;
        __syncthreads();
        if (tid == 0) {
            float t = 0.f;
            #pragma unroll
            for (int i = 0; i < 16; ++i) t += wsum[i];
            atomicAdd(out, t * (1.0f / (float)BB));
        }
    }
    #undef PW
}

// ---- verified R12 two-batch kernel, kept verbatim as launch fallback ----
__global__ __launch_bounds__(1024) void emd_sinkhorn2(
    const float* __restrict__ x, const float* __restrict__ y,
    float* __restrict__ Af, float* __restrict__ Bf,
    int* __restrict__ flags, float* __restrict__ out)
{
    extern __shared__ float S[];     // 12*NN floats = 96 KB
    __shared__ float pcomb[16 * 8];
    __shared__ float wsum[16];

    const int tid  = threadIdx.x;
    const int lane = tid & 63;
    const int w    = tid >> 6;
    const int pr   = w >> 1;
    const int jh   = w & 1;
    const int blk  = blockIdx.x;
    const int pair = blk & 7;
    const int q    = blk >> 3;
    const int b0   = pair * 2, b1 = b0 + 1;
    const int base0 = b0 * NN, base1 = b1 * NN;
    const int rloc  = q * 64 + pr * 8;
    int* f0 = flags + b0 * 128;
    int* f1 = flags + b1 * 128;

    float *sy00 = S,            *sy10 = S +  1*NN, *sy20 = S +  2*NN;
    float *sx00 = S +  3*NN,    *sx10 = S +  4*NN, *sx20 = S +  5*NN;
    float *sy01 = S +  6*NN,    *sy11 = S +  7*NN, *sy21 = S +  8*NN;
    float *sx01 = S +  9*NN,    *sx11 = S + 10*NN, *sx21 = S + 11*NN;

    #pragma unroll
    for (int v = 0; v < 2; ++v) {
        const int p = tid + (v << 10);
        {
            const float* px = x + 3 * (size_t)(base0 + p);
            sx00[p] = TWO_K2E * px[0]; sx10[p] = TWO_K2E * px[1]; sx20[p] = TWO_K2E * px[2];
            const float* py = y + 3 * (size_t)(base0 + p);
            sy00[p] = TWO_K2E * py[0]; sy10[p] = TWO_K2E * py[1]; sy20[p] = TWO_K2E * py[2];
        }
        {
            const float* px = x + 3 * (size_t)(base1 + p);
            sx01[p] = TWO_K2E * px[0]; sx11[p] = TWO_K2E * px[1]; sx21[p] = TWO_K2E * px[2];
            const float* py = y + 3 * (size_t)(base1 + p);
            sy01[p] = TWO_K2E * py[0]; sy11[p] = TWO_K2E * py[1]; sy21[p] = TWO_K2E * py[2];
        }
    }
    if (tid < 128) {
        const int bb  = tid >> 6;
        const int col = q * 64 + (tid & 63);
        const int bs  = bb ? base1 : base0;
        const float* py = y + 3 * (size_t)(bs + col);
        const float a = py[0], b = py[1], c = py[2];
        DSTORE(&Bf[bs + col], -K2E * (a*a + b*b + c*c));
    }
    __syncthreads();
    if (tid == 0) {
        __hip_atomic_store(f0 + q * 4, 1, __ATOMIC_RELEASE, __HIP_MEMORY_SCOPE_AGENT);
        __hip_atomic_store(f1 + q * 4, 1, __ATOMIC_RELEASE, __HIP_MEMORY_SCOPE_AGENT);
    }

    const int rr = ((lane & 1) << 2) | (lane & 2) | ((lane >> 2) & 1);

    #define PW2(pslot, pval, warr, tgt) do { __syncthreads();                   \
        if (tid == 0)                                                           \
            __hip_atomic_store((pslot), (pval), __ATOMIC_RELEASE,               \
                               __HIP_MEMORY_SCOPE_AGENT);                       \
        if (w == 0) {                                                           \
            for (;;) {                                                          \
                int vv = (lane < 32)                                            \
                    ? __hip_atomic_load((warr) + lane * 4, __ATOMIC_RELAXED,    \
                                        __HIP_MEMORY_SCOPE_AGENT)               \
                    : 0x7fffffff;                                               \
                if (__ballot(vv >= (tgt)) == ~0ULL) break;                      \
                __builtin_amdgcn_s_sleep(1);                                    \
            }                                                                   \
        }                                                                       \
        __syncthreads(); } while (0)

    #define WONLY2(warr, tgt) do { __syncthreads();                             \
        if (w == 0) {                                                           \
            for (;;) {                                                          \
                int vv = (lane < 32)                                            \
                    ? __hip_atomic_load((warr) + lane * 4, __ATOMIC_RELAXED,    \
                                        __HIP_MEMORY_SCOPE_AGENT)               \
                    : 0x7fffffff;                                               \
                if (__ballot(vv >= (tgt)) == ~0ULL) break;                      \
                __builtin_amdgcn_s_sleep(1);                                    \
            }                                                                   \
        }                                                                       \
        __syncthreads(); } while (0)

    WONLY2(f0, 1);

    float Aval0 = 0.f, Aval1 = 0.f;

    for (int it = 0; it < NITERS; ++it) {
        {
            float Sc = sumpassG(sx00, sx10, sx20, sy00, sy10, sy20, Bf + base0,
                                rloc, jh, lane, w, pcomb);
            Aval0 = LMU - __log2f(Sc);
            if (lane < 8 && jh == 0) DSTORE(&Af[base0 + rloc + rr], Aval0);
        }
        PW2(f0 + q * 4, 2 * it + 2, f1, 2 * it + 1);
        {
            float Sc = sumpassG(sx01, sx11, sx21, sy01, sy11, sy21, Bf + base1,
                                rloc, jh, lane, w, pcomb);
            Aval1 = LMU - __log2f(Sc);
            if (lane < 8 && jh == 0) DSTORE(&Af[base1 + rloc + rr], Aval1);
        }
        PW2(f1 + q * 4, 2 * it + 2, f0, 2 * it + 2);
        {
            float Sc = sumpassG(sy00, sy10, sy20, sx00, sx10, sx20, Af + base0,
                                rloc, jh, lane, w, pcomb);
            if (lane < 8 && jh == 0)
                DSTORE(&Bf[base0 + rloc + rr], LMU - __log2f(Sc));
        }
        PW2(f0 + q * 4, 2 * it + 3, f1, 2 * it + 2);
        {
            float Sc = sumpassG(sy01, sy11, sy21, sx01, sx11, sx21, Af + base1,
                                rloc, jh, lane, w, pcomb);
            if (lane < 8 && jh == 0)
                DSTORE(&Bf[base1 + rloc + rr], LMU - __log2f(Sc));
        }
        PW2(f1 + q * 4, 2 * it + 3, f0, 2 * it + 3);
    }
    WONLY2(f1, 2 * NITERS + 1);

    {
        float s = epilG(sx00, sx10, sx20, sy00, sy10, sy20, Bf + base0,
                        Aval0, rloc, jh, lane)
                + epilG(sx01, sx11, sx21, sy01, sy11, sy21, Bf + base1,
                        Aval1, rloc, jh, lane);
        #pragma unroll
        for (int m = 32; m > 0; m >>= 1) s += __shfl_xor(s, m, 64);
        if (lane == 0) wsum[w] = s;
        __syncthreads();
        if (tid == 0) {
            float t = 0.f;
            #pragma unroll
            for (int i = 0; i < 16; ++i) t += wsum[i];
            atomicAdd(out, t * (1.0f / (float)BB));
        }
    }
    #undef PW2
    #undef WONLY2
}

extern "C" void kernel_launch(void* const* d_in, const int* in_sizes, int n_in,
                              void* d_out, int out_size, void* d_ws, size_t ws_size,
                              hipStream_t stream) {
    const float* x = (const float*)d_in[0];
    const float* y = (const float*)d_in[1];
    float* out = (float*)d_out;
    char* ws = (char*)d_ws;

    int*   flags = (int*)ws;                                 // 16 x 32 x 16 B = 8 KB
    float* Af    = (float*)(ws + 8192);                      // 128 KB
    float* Bf    = (float*)(ws + 8192 + (size_t)BB*NN*sizeof(float));

    hipMemsetAsync(flags, 0, 8192, stream);
    hipMemsetAsync(out, 0, sizeof(float), stream);

    void* args[] = {(void*)&x, (void*)&y, (void*)&Af, (void*)&Bf,
                    (void*)&flags, (void*)&out};

    // Preferred: one-batch, 512 blocks, 2 blocks/CU. The cooperative launch
    // itself verifies co-residency (fails if VGPR>64 pushed occupancy down).
    const size_t shmem1 = (size_t)6 * NN * sizeof(float);    // 48 KB
    hipFuncSetAttribute((const void*)emd_sinkhorn1,
                        hipFuncAttributeMaxDynamicSharedMemorySize, (int)shmem1);
    hipError_t e = hipLaunchCooperativeKernel((const void*)emd_sinkhorn1,
                                              dim3(512), dim3(1024),
                                              args, shmem1, stream);
    if (e != hipSuccess) {
        // Fallback: verified two-batch kernel (256 blocks, 96 KB LDS).
        const size_t shmem2 = (size_t)12 * NN * sizeof(float);
        hipFuncSetAttribute((const void*)emd_sinkhorn2,
                            hipFuncAttributeMaxDynamicSharedMemorySize, (int)shmem2);
        hipError_t e2 = hipLaunchCooperativeKernel((const void*)emd_sinkhorn2,
                                                   dim3(256), dim3(1024),
                                                   args, shmem2, stream);
        if (e2 != hipSuccess) {
            hipLaunchKernelGGL(emd_sinkhorn2, dim3(256), dim3(1024), shmem2,
                               stream, x, y, Af, Bf, flags, out);
        }
    }
}